// Round 2
// baseline (1408.992 us; speedup 1.0000x reference)
//
#include <hip/hip_runtime.h>
#include <hip/hip_bf16.h>
#include <stdint.h>

// WSVectorQuantizer: N=65536 rows (D=256) vs K=1024 codewords.
// Pipeline: prep -> fp16-MFMA approx argmin w/ margin flagging -> exact fp32
// fallback on flagged rows -> gather+hist -> stats.

typedef float  v4f __attribute__((ext_vector_type(4)));
typedef _Float16 v8h __attribute__((ext_vector_type(8)));
typedef _Float16 v4h __attribute__((ext_vector_type(4)));

#define N_ROWS 65536
#define N_DICT 1024
#define DIMS   256
#define MARGIN 0.625f   // 2*err_max(0.25 @8sigma, Hoeffding-safe) + 0.125 quant

// ---------------- K1: prep ----------------
// 256 blocks x 256 thr: zero hist/counter, codebook fp32->fp16, cnorm (fp64 acc).
__global__ void k_prep(const float* __restrict__ cb, _Float16* __restrict__ cb_h,
                       float* __restrict__ cnA, float* __restrict__ cnB,
                       unsigned* __restrict__ hist, unsigned* __restrict__ counter) {
  const int b = blockIdx.x, t = threadIdx.x;
  if (b == 0) {
    for (int i = t; i < N_DICT; i += 256) hist[i] = 0u;
    if (t == 0) *counter = 0u;
  }
  // fp16 conversion: 65536 threads x 4 elems = 262144
  int gid = b * 256 + t;
  v4f v = ((const v4f*)cb)[gid];
  v4h h;
  h[0] = (_Float16)v[0]; h[1] = (_Float16)v[1];
  h[2] = (_Float16)v[2]; h[3] = (_Float16)v[3];
  ((v4h*)cb_h)[gid] = h;
  // cnorm: one wave per codeword (4 waves/block * 256 blocks = 1024)
  const int lane = t & 63, w = t >> 6;
  const int row = b * 4 + w;
  v4f u = ((const v4f*)cb)[row * 64 + lane];
  double s = (double)u[0]*u[0] + (double)u[1]*u[1]
           + (double)u[2]*u[2] + (double)u[3]*u[3];
  #pragma unroll
  for (int d = 1; d < 64; d <<= 1) s += __shfl_xor(s, d);
  if (lane == 0) { cnA[row] = (float)s; cnB[row] = (float)s + 1024.0f; }
}

// ---------------- K2: main fp16 MFMA argmin ----------------
// grid 256 x 512thr (8 waves). Wave owns 32 rows (2 m-tiles of 16), all K=256
// of z persistent in registers (fp16 frags). Loops 16 chunks of 64 codewords;
// B-frags read straight from global (L2-resident 512KB). No LDS, no barriers.
// Key packing: cost' = cnorm+1024-2*dot > 0 always (|2dot|<=760), so float
// bits are order-monotone; low 10 mantissa bits carry col (quant err <=0.125).
__launch_bounds__(512, 2)
__global__ void k_main(const float* __restrict__ z, const _Float16* __restrict__ cb_h,
                       const float* __restrict__ cnB, unsigned* __restrict__ out_idx,
                       unsigned* __restrict__ list, unsigned* __restrict__ counter) {
  const int t = threadIdx.x, lane = t & 63, w = t >> 6;
  const int l15 = lane & 15, q = lane >> 4;
  const int waverow = blockIdx.x * 256 + w * 32;

  // A fragments: af[m][kk], lane holds z[row=base+m*16+l15][k=kk*32+q*8 .. +8]
  v8h af[2][8];
  #pragma unroll
  for (int m = 0; m < 2; ++m) {
    const float* zp = z + (size_t)(waverow + m * 16 + l15) * DIMS + q * 8;
    #pragma unroll
    for (int kk = 0; kk < 8; ++kk) {
      v4f f0 = *(const v4f*)(zp + kk * 32);
      v4f f1 = *(const v4f*)(zp + kk * 32 + 4);
      v8h h;
      h[0]=(_Float16)f0[0]; h[1]=(_Float16)f0[1]; h[2]=(_Float16)f0[2]; h[3]=(_Float16)f0[3];
      h[4]=(_Float16)f1[0]; h[5]=(_Float16)f1[1]; h[6]=(_Float16)f1[2]; h[7]=(_Float16)f1[3];
      af[m][kk] = h;
    }
  }

  // running packed keys: state s = m*4+reg covers row = waverow+m*16+q*4+reg,
  // cols congruent to l15 (mod 16) within each chunk
  float v1[8], v2[8];
  #pragma unroll
  for (int s = 0; s < 8; ++s) { v1[s] = 1e30f; v2[s] = 1e30f; }
  const uint32_t MASK = 0xFFFFFC00u;

  for (int c = 0; c < 16; ++c) {
    const int n0 = c * 64;
    float cn[4]; int colv[4];
    #pragma unroll
    for (int t4 = 0; t4 < 4; ++t4) {
      colv[t4] = n0 + t4 * 16 + l15;
      cn[t4] = cnB[colv[t4]];
    }
    v4f acc[2][4];
    #pragma unroll
    for (int m = 0; m < 2; ++m)
      #pragma unroll
      for (int t4 = 0; t4 < 4; ++t4) acc[m][t4] = (v4f){0.f, 0.f, 0.f, 0.f};

    const _Float16* bp = cb_h + (size_t)(n0 + l15) * DIMS + q * 8;
    v8h b0[4], b1[4];
    #pragma unroll
    for (int t4 = 0; t4 < 4; ++t4) b0[t4] = *(const v8h*)(bp + t4 * 16 * DIMS);
    #pragma unroll
    for (int kk = 0; kk < 8; ++kk) {
      if (kk < 7) {
        #pragma unroll
        for (int t4 = 0; t4 < 4; ++t4)
          b1[t4] = *(const v8h*)(bp + t4 * 16 * DIMS + (kk + 1) * 32);
      }
      #pragma unroll
      for (int m = 0; m < 2; ++m)
        #pragma unroll
        for (int t4 = 0; t4 < 4; ++t4)
          acc[m][t4] = __builtin_amdgcn_mfma_f32_16x16x32_f16(af[m][kk], b0[t4], acc[m][t4], 0, 0, 0);
      if (kk < 7) {
        #pragma unroll
        for (int t4 = 0; t4 < 4; ++t4) b0[t4] = b1[t4];
      }
    }
    // epilogue: ~5 VALU/value, fully shadowed by MFMA via wave co-issue
    #pragma unroll
    for (int m = 0; m < 2; ++m)
      #pragma unroll
      for (int t4 = 0; t4 < 4; ++t4)
        #pragma unroll
        for (int r = 0; r < 4; ++r) {
          float costp = fmaf(acc[m][t4][r], -2.0f, cn[t4]);
          uint32_t kb = (__float_as_uint(costp) & MASK) | (uint32_t)colv[t4];
          float fk = __uint_as_float(kb);
          int s = m * 4 + r;
          float nv1 = fminf(v1[s], fk);
          v2[s] = fminf(v2[s], fmaxf(v1[s], fk));
          v1[s] = nv1;
        }
  }

  // merge (v1,v2) across the 16 lanes sharing q (xor of low 4 lane bits)
  #pragma unroll
  for (int s = 0; s < 8; ++s) {
    #pragma unroll
    for (int d = 1; d < 16; d <<= 1) {
      float o1 = __shfl_xor(v1[s], d);
      float o2 = __shfl_xor(v2[s], d);
      float nv1 = fminf(v1[s], o1);
      v2[s] = fminf(fminf(v2[s], o2), fmaxf(v1[s], o1));
      v1[s] = nv1;
    }
  }
  // writers: lane l15==s writes row (waverow + m*16 + q*4 + r)
  if (l15 < 8) {
    int s = l15, m = s >> 2, r = s & 3;
    int row = waverow + m * 16 + q * 4 + r;
    out_idx[row] = __float_as_uint(v1[s]) & 0x3FFu;
    if (v2[s] - v1[s] < MARGIN) {
      unsigned pos = atomicAdd(counter, 1u);
      list[pos] = (unsigned)row;
    }
  }
}

// ---------------- K3: exact fp32 fallback ----------------
// grid 512 x 256thr. Wave takes 8 flagged rows (rg=lane>>3), 8 col-lanes each
// (cg=lane&7, cols cg+8i). 8-way split fp32 accumulation ~ blocked-sum accuracy.
__global__ void k_fallback(const float* __restrict__ z, const float* __restrict__ cb,
                           const float* __restrict__ cnA,
                           const unsigned* __restrict__ list,
                           const unsigned* __restrict__ counter,
                           unsigned* __restrict__ out_idx) {
  const unsigned count = *counter;
  if (count == 0) return;
  const int t = threadIdx.x, lane = t & 63, w = t >> 6;
  const int rg = lane >> 3, cg = lane & 7;
  const unsigned gw = blockIdx.x * 4 + w;            // 2048 waves
  const unsigned ngroups = (count + 7) >> 3;
  for (unsigned g = gw; g < ngroups; g += 2048) {
    unsigned li = g * 8 + rg;
    unsigned row = list[li < count ? li : count - 1]; // dup tail: benign rewrite
    const float* zr = z + (size_t)row * DIMS;
    float best = 1e30f; int bestc = 0;
    for (int i = 0; i < 128; ++i) {
      int col = cg + 8 * i;
      const float* cp = cb + (size_t)col * DIMS;
      v4f a0 = (v4f){0.f,0.f,0.f,0.f}, a1 = (v4f){0.f,0.f,0.f,0.f};
      #pragma unroll 4
      for (int k = 0; k < DIMS; k += 8) {
        v4f z0 = *(const v4f*)(zr + k);
        v4f z1 = *(const v4f*)(zr + k + 4);
        v4f c0 = *(const v4f*)(cp + k);
        v4f c1 = *(const v4f*)(cp + k + 4);
        #pragma unroll
        for (int j = 0; j < 4; ++j) {
          a0[j] = fmaf(z0[j], c0[j], a0[j]);
          a1[j] = fmaf(z1[j], c1[j], a1[j]);
        }
      }
      float dot = ((a0[0]+a0[1]) + (a0[2]+a0[3])) + ((a1[0]+a1[1]) + (a1[2]+a1[3]));
      float cost = fmaf(dot, -2.0f, cnA[col]);
      if (cost < best) { best = cost; bestc = col; } // ascending col: first-wins
    }
    #pragma unroll
    for (int d = 1; d < 8; d <<= 1) {
      float ob = __shfl_xor(best, d);
      int   oc = __shfl_xor(bestc, d);
      if (ob < best || (ob == best && oc < bestc)) { best = ob; bestc = oc; }
    }
    if (cg == 0) out_idx[row] = (unsigned)bestc;
  }
}

// ---------------- K4: gather z_q + histogram ----------------
__global__ void k_gather(const float* __restrict__ cb, const unsigned* __restrict__ idx,
                         float* __restrict__ outz, unsigned* __restrict__ hist) {
  const int t = threadIdx.x, lane = t & 63, w = t >> 6;
  const int row = blockIdx.x * 4 + w;
  const unsigned id = idx[row];
  v4f v = *(const v4f*)(cb + (size_t)id * DIMS + lane * 4);
  *(v4f*)(outz + (size_t)row * DIMS + lane * 4) = v;
  if (lane == 0) atomicAdd(hist + id, 1u);
}

// ---------------- K5: loss + perplexity ----------------
__global__ void k_stats(const unsigned* __restrict__ hist, float* __restrict__ out) {
  const int t = threadIdx.x;
  float s = 0.f;
  for (int i = t; i < N_DICT; i += 256) {
    float p = (float)hist[i] * (1.0f / (float)N_ROWS);
    s += p * logf(p + 1e-10f);
  }
  #pragma unroll
  for (int d = 1; d < 64; d <<= 1) s += __shfl_xor(s, d);
  __shared__ float ls[4];
  if ((t & 63) == 0) ls[t >> 6] = s;
  __syncthreads();
  if (t == 0) {
    float tot = ls[0] + ls[1] + ls[2] + ls[3];
    out[16777216] = 0.0f;          // loss (eval)
    out[16777217] = expf(-tot);    // perplexity
  }
}

extern "C" void kernel_launch(void* const* d_in, const int* in_sizes, int n_in,
                              void* d_out, int out_size, void* d_ws, size_t ws_size,
                              hipStream_t stream) {
  const float* z  = (const float*)d_in[0];
  const float* cb = (const float*)d_in[1];
  // d_in[2] codebook_weight, d_in[3] flg_train: unused in eval path
  float* out = (float*)d_out;
  char* ws = (char*)d_ws;
  _Float16* cb_h    = (_Float16*)ws;                 // 512 KB
  float*    cnA     = (float*)(ws + 528384);         // raw ||c||^2
  float*    cnB     = (float*)(ws + 524288);         // ||c||^2 + 1024
  unsigned* idx     = (unsigned*)(ws + 532480);      // 256 KB
  unsigned* list    = (unsigned*)(ws + 794624);      // 256 KB
  unsigned* hist    = (unsigned*)(ws + 1056768);     // 4 KB
  unsigned* counter = (unsigned*)(ws + 1060864);

  k_prep    <<<256,   256, 0, stream>>>(cb, cb_h, cnA, cnB, hist, counter);
  k_main    <<<256,   512, 0, stream>>>(z, cb_h, cnB, idx, list, counter);
  k_fallback<<<512,   256, 0, stream>>>(z, cb, cnA, list, counter, idx);
  k_gather  <<<16384, 256, 0, stream>>>(cb, idx, out, hist);
  k_stats   <<<1,     256, 0, stream>>>(hist, out);
}

// Round 3
// 845.778 us; speedup vs baseline: 1.6659x; 1.6659x over previous
//
#include <hip/hip_runtime.h>
#include <hip/hip_bf16.h>
#include <stdint.h>

// WSVectorQuantizer: N=65536 rows (D=256) vs K=1024 codewords.
// Pipeline: prep -> fp16-MFMA approx argmin w/ margin flagging -> exact fp32
// task-parallel fallback (atomicMin u64 merge) -> final scatter -> gather+hist
// -> stats.

typedef float  v4f __attribute__((ext_vector_type(4)));
typedef _Float16 v8h __attribute__((ext_vector_type(8)));
typedef _Float16 v4h __attribute__((ext_vector_type(4)));

#define N_ROWS 65536
#define N_DICT 1024
#define DIMS   256
#define MARGIN 0.625f   // 2*err_max(0.25 @8sigma) + 0.125 quant

// ---------------- K1: prep ----------------
__global__ void k_prep(const float* __restrict__ cb, _Float16* __restrict__ cb_h,
                       float* __restrict__ cnA, float* __restrict__ cnB,
                       unsigned* __restrict__ hist, unsigned* __restrict__ counter) {
  const int b = blockIdx.x, t = threadIdx.x;
  if (b == 0) {
    for (int i = t; i < N_DICT; i += 256) hist[i] = 0u;
    if (t == 0) *counter = 0u;
  }
  int gid = b * 256 + t;
  v4f v = ((const v4f*)cb)[gid];
  v4h h;
  h[0] = (_Float16)v[0]; h[1] = (_Float16)v[1];
  h[2] = (_Float16)v[2]; h[3] = (_Float16)v[3];
  ((v4h*)cb_h)[gid] = h;
  const int lane = t & 63, w = t >> 6;
  const int row = b * 4 + w;
  v4f u = ((const v4f*)cb)[row * 64 + lane];
  double s = (double)u[0]*u[0] + (double)u[1]*u[1]
           + (double)u[2]*u[2] + (double)u[3]*u[3];
  #pragma unroll
  for (int d = 1; d < 64; d <<= 1) s += __shfl_xor(s, d);
  if (lane == 0) { cnA[row] = (float)s; cnB[row] = (float)s + 1024.0f; }
}

// ---------------- K2: main fp16 MFMA argmin ----------------
__launch_bounds__(512, 2)
__global__ void k_main(const float* __restrict__ z, const _Float16* __restrict__ cb_h,
                       const float* __restrict__ cnB, unsigned* __restrict__ out_idx,
                       unsigned* __restrict__ list, unsigned* __restrict__ counter,
                       unsigned long long* __restrict__ packed) {
  const int t = threadIdx.x, lane = t & 63, w = t >> 6;
  const int l15 = lane & 15, q = lane >> 4;
  const int waverow = blockIdx.x * 256 + w * 32;

  v8h af[2][8];
  #pragma unroll
  for (int m = 0; m < 2; ++m) {
    const float* zp = z + (size_t)(waverow + m * 16 + l15) * DIMS + q * 8;
    #pragma unroll
    for (int kk = 0; kk < 8; ++kk) {
      v4f f0 = *(const v4f*)(zp + kk * 32);
      v4f f1 = *(const v4f*)(zp + kk * 32 + 4);
      v8h h;
      h[0]=(_Float16)f0[0]; h[1]=(_Float16)f0[1]; h[2]=(_Float16)f0[2]; h[3]=(_Float16)f0[3];
      h[4]=(_Float16)f1[0]; h[5]=(_Float16)f1[1]; h[6]=(_Float16)f1[2]; h[7]=(_Float16)f1[3];
      af[m][kk] = h;
    }
  }

  float v1[8], v2[8];
  #pragma unroll
  for (int s = 0; s < 8; ++s) { v1[s] = 1e30f; v2[s] = 1e30f; }
  const uint32_t MASK = 0xFFFFFC00u;

  for (int c = 0; c < 16; ++c) {
    const int n0 = c * 64;
    float cn[4]; int colv[4];
    #pragma unroll
    for (int t4 = 0; t4 < 4; ++t4) {
      colv[t4] = n0 + t4 * 16 + l15;
      cn[t4] = cnB[colv[t4]];
    }
    v4f acc[2][4];
    #pragma unroll
    for (int m = 0; m < 2; ++m)
      #pragma unroll
      for (int t4 = 0; t4 < 4; ++t4) acc[m][t4] = (v4f){0.f, 0.f, 0.f, 0.f};

    const _Float16* bp = cb_h + (size_t)(n0 + l15) * DIMS + q * 8;
    v8h b0[4], b1[4];
    #pragma unroll
    for (int t4 = 0; t4 < 4; ++t4) b0[t4] = *(const v8h*)(bp + t4 * 16 * DIMS);
    #pragma unroll
    for (int kk = 0; kk < 8; ++kk) {
      if (kk < 7) {
        #pragma unroll
        for (int t4 = 0; t4 < 4; ++t4)
          b1[t4] = *(const v8h*)(bp + t4 * 16 * DIMS + (kk + 1) * 32);
      }
      #pragma unroll
      for (int m = 0; m < 2; ++m)
        #pragma unroll
        for (int t4 = 0; t4 < 4; ++t4)
          acc[m][t4] = __builtin_amdgcn_mfma_f32_16x16x32_f16(af[m][kk], b0[t4], acc[m][t4], 0, 0, 0);
      if (kk < 7) {
        #pragma unroll
        for (int t4 = 0; t4 < 4; ++t4) b0[t4] = b1[t4];
      }
    }
    #pragma unroll
    for (int m = 0; m < 2; ++m)
      #pragma unroll
      for (int t4 = 0; t4 < 4; ++t4)
        #pragma unroll
        for (int r = 0; r < 4; ++r) {
          float costp = fmaf(acc[m][t4][r], -2.0f, cn[t4]);
          uint32_t kb = (__float_as_uint(costp) & MASK) | (uint32_t)colv[t4];
          float fk = __uint_as_float(kb);
          int s = m * 4 + r;
          float nv1 = fminf(v1[s], fk);
          v2[s] = fminf(v2[s], fmaxf(v1[s], fk));
          v1[s] = nv1;
        }
  }

  #pragma unroll
  for (int s = 0; s < 8; ++s) {
    #pragma unroll
    for (int d = 1; d < 16; d <<= 1) {
      float o1 = __shfl_xor(v1[s], d);
      float o2 = __shfl_xor(v2[s], d);
      float nv1 = fminf(v1[s], o1);
      v2[s] = fminf(fminf(v2[s], o2), fmaxf(v1[s], o1));
      v1[s] = nv1;
    }
  }
  if (l15 < 8) {
    int s = l15, m = s >> 2, r = s & 3;
    int row = waverow + m * 16 + q * 4 + r;
    out_idx[row] = __float_as_uint(v1[s]) & 0x3FFu;
    if (v2[s] - v1[s] < MARGIN) {
      packed[row] = ~0ull;                  // init merge slot before fallback
      unsigned pos = atomicAdd(counter, 1u);
      list[pos] = (unsigned)row;
    }
  }
}

// ---------------- K3: exact fp32 fallback, task-parallel ----------------
// Task = (8-row group from list) x (64-col chunk); 16 chunks/group.
// Wave lanes: rg=lane>>3 (row), cg=lane&7; lane scans cols chunk*64+cg+8i.
// Exact fp32 split-8 accumulation; merge via u64 atomicMin on
// (costB_bits<<32)|col  — costB = cnB[col]-2*dot > 0 always, bit-monotone;
// low col wins ties = np first-occurrence argmin.
__global__ void k_fallback(const float* __restrict__ z, const float* __restrict__ cb,
                           const float* __restrict__ cnB,
                           const unsigned* __restrict__ list,
                           const unsigned* __restrict__ counter,
                           unsigned long long* __restrict__ packed) {
  const unsigned count = *counter;
  if (count == 0) return;
  const int t = threadIdx.x, lane = t & 63, w = t >> 6;
  const int rg = lane >> 3, cg = lane & 7;
  const unsigned gw = blockIdx.x * 4 + w;                  // 4096 waves
  const unsigned ngroups = (count + 7) >> 3;
  const unsigned ntasks = ngroups * 16;
  for (unsigned task = gw; task < ntasks; task += 4096) {
    const unsigned g = task >> 4, chunk = task & 15;
    unsigned li = g * 8 + rg;
    unsigned row = list[li < count ? li : count - 1];      // dup tail: benign
    const float* zr = z + (size_t)row * DIMS;
    unsigned long long best = ~0ull;
    #pragma unroll
    for (int i = 0; i < 8; ++i) {
      int col = (int)chunk * 64 + cg + 8 * i;
      const float* cp = cb + (size_t)col * DIMS;
      v4f a0 = (v4f){0.f,0.f,0.f,0.f}, a1 = (v4f){0.f,0.f,0.f,0.f};
      #pragma unroll 4
      for (int k = 0; k < DIMS; k += 8) {
        v4f z0 = *(const v4f*)(zr + k);
        v4f z1 = *(const v4f*)(zr + k + 4);
        v4f c0 = *(const v4f*)(cp + k);
        v4f c1 = *(const v4f*)(cp + k + 4);
        #pragma unroll
        for (int j = 0; j < 4; ++j) {
          a0[j] = fmaf(z0[j], c0[j], a0[j]);
          a1[j] = fmaf(z1[j], c1[j], a1[j]);
        }
      }
      float dot = ((a0[0]+a0[1]) + (a0[2]+a0[3])) + ((a1[0]+a1[1]) + (a1[2]+a1[3]));
      float costB = fmaf(dot, -2.0f, cnB[col]);            // > 0 always
      unsigned long long key =
          ((unsigned long long)__float_as_uint(costB) << 32) | (unsigned)col;
      best = key < best ? key : best;
    }
    #pragma unroll
    for (int d = 1; d < 8; d <<= 1) {
      unsigned long long ob = __shfl_xor(best, d);
      best = ob < best ? ob : best;
    }
    if (cg == 0) atomicMin(&packed[row], best);
  }
}

// ---------------- K3b: scatter winning cols back to idx ----------------
__global__ void k_final(const unsigned* __restrict__ list,
                        const unsigned* __restrict__ counter,
                        const unsigned long long* __restrict__ packed,
                        unsigned* __restrict__ out_idx) {
  const unsigned count = *counter;
  for (unsigned i = blockIdx.x * 256 + threadIdx.x; i < count; i += 256 * 256) {
    unsigned row = list[i];
    out_idx[row] = (unsigned)(packed[row] & 0x3FFull);
  }
}

// ---------------- K4: gather z_q + histogram ----------------
__global__ void k_gather(const float* __restrict__ cb, const unsigned* __restrict__ idx,
                         float* __restrict__ outz, unsigned* __restrict__ hist) {
  const int t = threadIdx.x, lane = t & 63, w = t >> 6;
  const int row = blockIdx.x * 4 + w;
  const unsigned id = idx[row];
  v4f v = *(const v4f*)(cb + (size_t)id * DIMS + lane * 4);
  *(v4f*)(outz + (size_t)row * DIMS + lane * 4) = v;
  if (lane == 0) atomicAdd(hist + id, 1u);
}

// ---------------- K5: loss + perplexity ----------------
__global__ void k_stats(const unsigned* __restrict__ hist, float* __restrict__ out) {
  const int t = threadIdx.x;
  float s = 0.f;
  for (int i = t; i < N_DICT; i += 256) {
    float p = (float)hist[i] * (1.0f / (float)N_ROWS);
    s += p * logf(p + 1e-10f);
  }
  #pragma unroll
  for (int d = 1; d < 64; d <<= 1) s += __shfl_xor(s, d);
  __shared__ float ls[4];
  if ((t & 63) == 0) ls[t >> 6] = s;
  __syncthreads();
  if (t == 0) {
    float tot = ls[0] + ls[1] + ls[2] + ls[3];
    out[16777216] = 0.0f;          // loss (eval)
    out[16777217] = expf(-tot);    // perplexity
  }
}

extern "C" void kernel_launch(void* const* d_in, const int* in_sizes, int n_in,
                              void* d_out, int out_size, void* d_ws, size_t ws_size,
                              hipStream_t stream) {
  const float* z  = (const float*)d_in[0];
  const float* cb = (const float*)d_in[1];
  float* out = (float*)d_out;
  char* ws = (char*)d_ws;
  _Float16* cb_h    = (_Float16*)ws;                          // 512 KB
  float*    cnB     = (float*)(ws + 524288);                  // ||c||^2+1024
  float*    cnA     = (float*)(ws + 528384);                  // raw ||c||^2
  unsigned* idx     = (unsigned*)(ws + 532480);               // 256 KB
  unsigned* list    = (unsigned*)(ws + 794624);               // 256 KB
  unsigned* hist    = (unsigned*)(ws + 1056768);              // 4 KB
  unsigned* counter = (unsigned*)(ws + 1060864);
  unsigned long long* packed = (unsigned long long*)(ws + 1060872); // 512 KB

  k_prep    <<<256,   256, 0, stream>>>(cb, cb_h, cnA, cnB, hist, counter);
  k_main    <<<256,   512, 0, stream>>>(z, cb_h, cnB, idx, list, counter, packed);
  k_fallback<<<1024,  256, 0, stream>>>(z, cb, cnB, list, counter, packed);
  k_final   <<<256,   256, 0, stream>>>(list, counter, packed, idx);
  k_gather  <<<16384, 256, 0, stream>>>(cb, idx, out, hist);
  k_stats   <<<1,     256, 0, stream>>>(hist, out);
}

// Round 4
// 744.868 us; speedup vs baseline: 1.8916x; 1.1355x over previous
//
#include <hip/hip_runtime.h>
#include <hip/hip_bf16.h>
#include <stdint.h>

// WSVectorQuantizer: N=65536 rows (D=256) vs K=1024 codewords.
// v4: split-fp16 MFMA (z=h+l, c=ch+cl; h*ch + l*ch + h*cl) gives ~fp32-exact
// costs -> margin 4e-3 flags only ~1e-3 of rows -> tiny fp64 exact fallback.

typedef float  v4f __attribute__((ext_vector_type(4)));
typedef _Float16 v8h __attribute__((ext_vector_type(8)));
typedef _Float16 v4h __attribute__((ext_vector_type(4)));

#define N_ROWS 65536
#define N_DICT 1024
#define DIMS   256
#define MARGIN 4e-3f   // ~10x worst-tail of split-fp16 error (~4e-4)

// ---------------- K1: prep ----------------
// codebook -> (ch, cl) split-fp16; exact ||c||^2 (fp64 acc, ->fp32); zero hist.
__global__ void k_prep(const float* __restrict__ cb, _Float16* __restrict__ cb_h,
                       _Float16* __restrict__ cb_l, float* __restrict__ cnA,
                       unsigned* __restrict__ hist, unsigned* __restrict__ counter) {
  const int b = blockIdx.x, t = threadIdx.x;
  if (b == 0) {
    for (int i = t; i < N_DICT; i += 256) hist[i] = 0u;
    if (t == 0) *counter = 0u;
  }
  int gid = b * 256 + t;                      // 65536 threads x 4 elems
  v4f v = ((const v4f*)cb)[gid];
  v4h h, l;
  #pragma unroll
  for (int j = 0; j < 4; ++j) {
    h[j] = (_Float16)v[j];
    float r = v[j] - (float)h[j];             // exact (Sterbenz)
    l[j] = (_Float16)r;                       // residual exact to 2^-22 |v|
  }
  ((v4h*)cb_h)[gid] = h;
  ((v4h*)cb_l)[gid] = l;
  const int lane = t & 63, w = t >> 6;
  const int row = b * 4 + w;
  v4f u = ((const v4f*)cb)[row * 64 + lane];
  double s = (double)u[0]*u[0] + (double)u[1]*u[1]
           + (double)u[2]*u[2] + (double)u[3]*u[3];
  #pragma unroll
  for (int d = 1; d < 64; d <<= 1) s += __shfl_xor(s, d);
  if (lane == 0) cnA[row] = (float)s;
}

// ---------------- K2: main split-fp16 MFMA argmin ----------------
// 1024 blocks x 256 thr (4 waves). Wave owns 16 rows; A-frags h,l persistent
// (64 VGPR). 16 chunks of 64 cols; per kk: load ch,cl frags, 3 MFMA each t4.
// Track (min1, col1, min2) per state; in-lane candidate cols strictly
// ascending -> strict < keeps lowest col (np argmin tie rule).
__launch_bounds__(256, 3)
__global__ void k_main(const float* __restrict__ z, const _Float16* __restrict__ cb_h,
                       const _Float16* __restrict__ cb_l, const float* __restrict__ cnA,
                       unsigned* __restrict__ out_idx,
                       unsigned* __restrict__ list, unsigned* __restrict__ counter) {
  const int t = threadIdx.x, lane = t & 63, w = t >> 6;
  const int l15 = lane & 15, q = lane >> 4;
  const int waverow = (blockIdx.x * 4 + w) * 16;

  // A fragments: lane holds z[waverow+l15][kk*32 + q*8 .. +8], split h/l
  v8h ah[8], al[8];
  {
    const float* zp = z + (size_t)(waverow + l15) * DIMS + q * 8;
    #pragma unroll
    for (int kk = 0; kk < 8; ++kk) {
      v4f f0 = *(const v4f*)(zp + kk * 32);
      v4f f1 = *(const v4f*)(zp + kk * 32 + 4);
      v8h hh, ll;
      #pragma unroll
      for (int j = 0; j < 4; ++j) {
        hh[j] = (_Float16)f0[j];
        float r = f0[j] - (float)hh[j];
        ll[j] = (_Float16)r;
        hh[4 + j] = (_Float16)f1[j];
        r = f1[j] - (float)hh[4 + j];
        ll[4 + j] = (_Float16)r;
      }
      ah[kk] = hh; al[kk] = ll;
    }
  }

  // state r (0..3) covers row = waverow + q*4 + r, candidate cols = l15 mod 16
  float m1[4], m2[4]; int c1[4];
  #pragma unroll
  for (int r = 0; r < 4; ++r) { m1[r] = 1e30f; m2[r] = 1e30f; c1[r] = 0; }

  for (int c = 0; c < 16; ++c) {
    const int n0 = c * 64;
    float cn[4]; int colv[4];
    #pragma unroll
    for (int t4 = 0; t4 < 4; ++t4) {
      colv[t4] = n0 + t4 * 16 + l15;
      cn[t4] = cnA[colv[t4]];
    }
    v4f acc[4];
    #pragma unroll
    for (int t4 = 0; t4 < 4; ++t4) acc[t4] = (v4f){0.f, 0.f, 0.f, 0.f};

    const _Float16* bh = cb_h + (size_t)(n0 + l15) * DIMS + q * 8;
    const _Float16* bl = cb_l + (size_t)(n0 + l15) * DIMS + q * 8;
    #pragma unroll
    for (int kk = 0; kk < 8; ++kk) {
      v8h b_h[4], b_l[4];
      #pragma unroll
      for (int t4 = 0; t4 < 4; ++t4) b_h[t4] = *(const v8h*)(bh + t4 * 16 * DIMS + kk * 32);
      #pragma unroll
      for (int t4 = 0; t4 < 4; ++t4) b_l[t4] = *(const v8h*)(bl + t4 * 16 * DIMS + kk * 32);
      #pragma unroll
      for (int t4 = 0; t4 < 4; ++t4)
        acc[t4] = __builtin_amdgcn_mfma_f32_16x16x32_f16(ah[kk], b_h[t4], acc[t4], 0, 0, 0);
      #pragma unroll
      for (int t4 = 0; t4 < 4; ++t4)
        acc[t4] = __builtin_amdgcn_mfma_f32_16x16x32_f16(al[kk], b_h[t4], acc[t4], 0, 0, 0);
      #pragma unroll
      for (int t4 = 0; t4 < 4; ++t4)
        acc[t4] = __builtin_amdgcn_mfma_f32_16x16x32_f16(ah[kk], b_l[t4], acc[t4], 0, 0, 0);
    }
    // epilogue: ~5 VALU/candidate
    #pragma unroll
    for (int t4 = 0; t4 < 4; ++t4)
      #pragma unroll
      for (int r = 0; r < 4; ++r) {
        float cost = fmaf(acc[t4][r], -2.0f, cn[t4]);
        bool lt = cost < m1[r];
        m2[r] = fminf(m2[r], fmaxf(m1[r], cost));
        m1[r] = fminf(m1[r], cost);
        c1[r] = lt ? colv[t4] : c1[r];
      }
  }

  // butterfly merge over the 16 lanes sharing q (lexicographic on (m1, col))
  #pragma unroll
  for (int d = 1; d < 16; d <<= 1) {
    #pragma unroll
    for (int r = 0; r < 4; ++r) {
      float om1 = __shfl_xor(m1[r], d);
      float om2 = __shfl_xor(m2[r], d);
      int   oc1 = __shfl_xor(c1[r], d);
      float mx = fmaxf(m1[r], om1);
      m2[r] = fminf(fminf(m2[r], om2), mx);
      bool take = (om1 < m1[r]) || (om1 == m1[r] && oc1 < c1[r]);
      m1[r] = take ? om1 : m1[r];
      c1[r] = take ? oc1 : c1[r];
    }
  }
  if (l15 < 4) {
    const int r = l15;
    const int row = waverow + q * 4 + r;
    out_idx[row] = (unsigned)c1[r];
    if (m2[r] - m1[r] < MARGIN) {
      unsigned pos = atomicAdd(counter, 1u);
      list[pos] = (unsigned)row;
    }
  }
}

// ---------------- K3: fp64 true-argmin fallback (flagged rows only) ----------------
// 256 blocks x 256 thr = 1024 waves; one wave per flagged row. Lane scans 16
// cols (ci*64+lane); fp64 dot + fp64 ||c||^2 recomputed inline -> true argmin.
__global__ void k_fallback(const float* __restrict__ z, const float* __restrict__ cb,
                           const unsigned* __restrict__ list,
                           const unsigned* __restrict__ counter,
                           unsigned* __restrict__ out_idx) {
  const unsigned count = *counter;
  if (count == 0) return;
  const int t = threadIdx.x, lane = t & 63, w = t >> 6;
  const unsigned gw = blockIdx.x * 4 + w;              // 1024 waves
  for (unsigned g = gw; g < count; g += 1024) {
    const unsigned row = list[g];
    const float* zr = z + (size_t)row * DIMS;
    double best = 1e300; int bc = 0;
    for (int ci = 0; ci < 16; ++ci) {                  // in-lane cols ascending
      const int col = ci * 64 + lane;
      const float* cp = cb + (size_t)col * DIMS;
      double a0 = 0, a1 = 0, a2 = 0, a3 = 0, q0 = 0, q1 = 0;
      #pragma unroll 4
      for (int k = 0; k < DIMS; k += 4) {
        v4f zz = *(const v4f*)(zr + k);
        v4f cc = *(const v4f*)(cp + k);
        a0 = fma((double)zz[0], (double)cc[0], a0);
        a1 = fma((double)zz[1], (double)cc[1], a1);
        a2 = fma((double)zz[2], (double)cc[2], a2);
        a3 = fma((double)zz[3], (double)cc[3], a3);
        q0 = fma((double)cc[0], (double)cc[0], q0);
        q1 = fma((double)cc[1], (double)cc[1], q1);
        q0 = fma((double)cc[2], (double)cc[2], q0);
        q1 = fma((double)cc[3], (double)cc[3], q1);
      }
      double cost = (q0 + q1) - 2.0 * ((a0 + a1) + (a2 + a3));
      if (cost < best) { best = cost; bc = col; }      // strict <: lowest col
    }
    #pragma unroll
    for (int d = 1; d < 64; d <<= 1) {
      double ob = __shfl_xor(best, d);
      int    oc = __shfl_xor(bc, d);
      if (ob < best || (ob == best && oc < bc)) { best = ob; bc = oc; }
    }
    if (lane == 0) out_idx[row] = (unsigned)bc;
  }
}

// ---------------- K4: gather z_q + histogram ----------------
__global__ void k_gather(const float* __restrict__ cb, const unsigned* __restrict__ idx,
                         float* __restrict__ outz, unsigned* __restrict__ hist) {
  const int t = threadIdx.x, lane = t & 63, w = t >> 6;
  const int row = blockIdx.x * 4 + w;
  const unsigned id = idx[row];
  v4f v = *(const v4f*)(cb + (size_t)id * DIMS + lane * 4);
  *(v4f*)(outz + (size_t)row * DIMS + lane * 4) = v;
  if (lane == 0) atomicAdd(hist + id, 1u);
}

// ---------------- K5: loss + perplexity ----------------
__global__ void k_stats(const unsigned* __restrict__ hist, float* __restrict__ out) {
  const int t = threadIdx.x;
  float s = 0.f;
  for (int i = t; i < N_DICT; i += 256) {
    float p = (float)hist[i] * (1.0f / (float)N_ROWS);
    s += p * logf(p + 1e-10f);
  }
  #pragma unroll
  for (int d = 1; d < 64; d <<= 1) s += __shfl_xor(s, d);
  __shared__ float ls[4];
  if ((t & 63) == 0) ls[t >> 6] = s;
  __syncthreads();
  if (t == 0) {
    float tot = ls[0] + ls[1] + ls[2] + ls[3];
    out[16777216] = 0.0f;          // loss (eval)
    out[16777217] = expf(-tot);    // perplexity
  }
}

extern "C" void kernel_launch(void* const* d_in, const int* in_sizes, int n_in,
                              void* d_out, int out_size, void* d_ws, size_t ws_size,
                              hipStream_t stream) {
  const float* z  = (const float*)d_in[0];
  const float* cb = (const float*)d_in[1];
  float* out = (float*)d_out;
  char* ws = (char*)d_ws;
  _Float16* cb_h    = (_Float16*)ws;                   // 512 KB
  _Float16* cb_l    = (_Float16*)(ws + 524288);        // 512 KB
  float*    cnA     = (float*)(ws + 1048576);          // 4 KB
  unsigned* idx     = (unsigned*)(ws + 1052672);       // 256 KB
  unsigned* list    = (unsigned*)(ws + 1314816);       // 256 KB
  unsigned* hist    = (unsigned*)(ws + 1576960);       // 4 KB
  unsigned* counter = (unsigned*)(ws + 1581056);

  k_prep    <<<256,   256, 0, stream>>>(cb, cb_h, cb_l, cnA, hist, counter);
  k_main    <<<1024,  256, 0, stream>>>(z, cb_h, cb_l, cnA, idx, list, counter);
  k_fallback<<<256,   256, 0, stream>>>(z, cb, list, counter, idx);
  k_gather  <<<16384, 256, 0, stream>>>(cb, idx, out, hist);
  k_stats   <<<1,     256, 0, stream>>>(hist, out);
}

// Round 5
// 492.811 us; speedup vs baseline: 2.8591x; 1.5115x over previous
//
#include <hip/hip_runtime.h>
#include <hip/hip_bf16.h>
#include <stdint.h>

// WSVectorQuantizer: N=65536 rows (D=256) vs K=1024 codewords.
// v5: split-fp16 MFMA with codebook PRE-SWIZZLED into MFMA B-fragment order
// (coalesced 1KiB wave-loads), launch_bounds(256,2) so A-frags stay in VGPRs.

typedef float  v4f __attribute__((ext_vector_type(4)));
typedef _Float16 v8h __attribute__((ext_vector_type(8)));
typedef _Float16 v4h __attribute__((ext_vector_type(4)));

#define N_ROWS 65536
#define N_DICT 1024
#define DIMS   256
#define MARGIN 4e-3f   // ~10x worst-tail of split-fp16 error (~4e-4)

// ---------------- K1: prep ----------------
// codebook -> (h,l) split-fp16 stored in MFMA B-fragment order:
// for chunk c (64 cols), kk (k-step of 32), t4 (16-col group), the 64 lanes'
// v8h fragments are contiguous: off = ((c*8+kk)*4+t4)*512 + lane*8 + j.
// lane = q*16+l15 covers col = c*64+t4*16+l15, k = kk*32+q*8+j.
__global__ void k_prep(const float* __restrict__ cb, _Float16* __restrict__ swz_h,
                       _Float16* __restrict__ swz_l, float* __restrict__ cnA,
                       unsigned* __restrict__ hist, unsigned* __restrict__ counter) {
  const int b = blockIdx.x, t = threadIdx.x;
  if (b == 0) {
    for (int i = t; i < N_DICT; i += 256) hist[i] = 0u;
    if (t == 0) *counter = 0u;
  }
  const int gid = b * 256 + t;                 // 65536 threads x 4 elems
  const int col = gid >> 6;
  const int k0  = (gid & 63) * 4;
  v4f v = ((const v4f*)cb)[gid];
  v4h h, l;
  #pragma unroll
  for (int j = 0; j < 4; ++j) {
    h[j] = (_Float16)v[j];
    float r = v[j] - (float)h[j];              // exact residual
    l[j] = (_Float16)r;                        // |err| <= 2^-22 |v|
  }
  const int c = col >> 6, t4 = (col >> 4) & 3, l15 = col & 15;
  const int kk = k0 >> 5, q = (k0 >> 3) & 3, j0 = k0 & 7;
  const size_t off = (size_t)(((c * 8 + kk) * 4 + t4) * 512 + (q * 16 + l15) * 8 + j0);
  *(v4h*)(swz_h + off) = h;
  *(v4h*)(swz_l + off) = l;
  // exact ||c||^2 (fp64 acc): one wave per codeword
  const int lane = t & 63, w = t >> 6;
  const int row = b * 4 + w;
  v4f u = ((const v4f*)cb)[row * 64 + lane];
  double s = (double)u[0]*u[0] + (double)u[1]*u[1]
           + (double)u[2]*u[2] + (double)u[3]*u[3];
  #pragma unroll
  for (int d = 1; d < 64; d <<= 1) s += __shfl_xor(s, d);
  if (lane == 0) cnA[row] = (float)s;
}

// ---------------- K2: main split-fp16 MFMA argmin ----------------
// 1024 blocks x 256 thr (4 waves). Wave owns 16 rows; A-frags h,l persistent.
// 16 chunks of 64 cols; per kk: coalesced 1KiB wave-loads of swizzled h,l
// frags, 12 MFMAs (h*ch + l*ch + h*cl). Track (min1,col1,min2); in-lane cols
// ascending -> strict < keeps lowest col (np tie rule).
__launch_bounds__(256, 2)
__global__ void k_main(const float* __restrict__ z, const _Float16* __restrict__ swz_h,
                       const _Float16* __restrict__ swz_l, const float* __restrict__ cnA,
                       unsigned* __restrict__ out_idx,
                       unsigned* __restrict__ list, unsigned* __restrict__ counter) {
  const int t = threadIdx.x, lane = t & 63, w = t >> 6;
  const int l15 = lane & 15, q = lane >> 4;
  const int waverow = (blockIdx.x * 4 + w) * 16;

  // A fragments: lane holds z[waverow+l15][kk*32 + q*8 .. +8], split h/l
  v8h ah[8], al[8];
  {
    const float* zp = z + (size_t)(waverow + l15) * DIMS + q * 8;
    #pragma unroll
    for (int kk = 0; kk < 8; ++kk) {
      v4f f0 = *(const v4f*)(zp + kk * 32);
      v4f f1 = *(const v4f*)(zp + kk * 32 + 4);
      v8h hh, ll;
      #pragma unroll
      for (int j = 0; j < 4; ++j) {
        hh[j] = (_Float16)f0[j];
        float r = f0[j] - (float)hh[j];
        ll[j] = (_Float16)r;
        hh[4 + j] = (_Float16)f1[j];
        r = f1[j] - (float)hh[4 + j];
        ll[4 + j] = (_Float16)r;
      }
      ah[kk] = hh; al[kk] = ll;
    }
  }

  float m1[4], m2[4]; int c1[4];
  #pragma unroll
  for (int r = 0; r < 4; ++r) { m1[r] = 1e30f; m2[r] = 1e30f; c1[r] = 0; }

  for (int c = 0; c < 16; ++c) {
    const int n0 = c * 64;
    float cn[4]; int colv[4];
    #pragma unroll
    for (int t4 = 0; t4 < 4; ++t4) {
      colv[t4] = n0 + t4 * 16 + l15;
      cn[t4] = cnA[colv[t4]];
    }
    v4f acc[4];
    #pragma unroll
    for (int t4 = 0; t4 < 4; ++t4) acc[t4] = (v4f){0.f, 0.f, 0.f, 0.f};

    // coalesced fragment streams: 32 blocks of 1KiB per chunk, h and l
    const _Float16* bh = swz_h + (size_t)(c * 32) * 512 + lane * 8;
    const _Float16* bl = swz_l + (size_t)(c * 32) * 512 + lane * 8;
    #pragma unroll
    for (int kk = 0; kk < 8; ++kk) {
      v8h b_h[4], b_l[4];
      #pragma unroll
      for (int t4 = 0; t4 < 4; ++t4)
        b_h[t4] = *(const v8h*)(bh + (size_t)(kk * 4 + t4) * 512);
      #pragma unroll
      for (int t4 = 0; t4 < 4; ++t4)
        b_l[t4] = *(const v8h*)(bl + (size_t)(kk * 4 + t4) * 512);
      #pragma unroll
      for (int t4 = 0; t4 < 4; ++t4)
        acc[t4] = __builtin_amdgcn_mfma_f32_16x16x32_f16(ah[kk], b_h[t4], acc[t4], 0, 0, 0);
      #pragma unroll
      for (int t4 = 0; t4 < 4; ++t4)
        acc[t4] = __builtin_amdgcn_mfma_f32_16x16x32_f16(al[kk], b_h[t4], acc[t4], 0, 0, 0);
      #pragma unroll
      for (int t4 = 0; t4 < 4; ++t4)
        acc[t4] = __builtin_amdgcn_mfma_f32_16x16x32_f16(ah[kk], b_l[t4], acc[t4], 0, 0, 0);
    }
    #pragma unroll
    for (int t4 = 0; t4 < 4; ++t4)
      #pragma unroll
      for (int r = 0; r < 4; ++r) {
        float cost = fmaf(acc[t4][r], -2.0f, cn[t4]);
        bool lt = cost < m1[r];
        m2[r] = fminf(m2[r], fmaxf(m1[r], cost));
        m1[r] = fminf(m1[r], cost);
        c1[r] = lt ? colv[t4] : c1[r];
      }
  }

  // butterfly merge over the 16 lanes sharing q (lexicographic on (m1, col))
  #pragma unroll
  for (int d = 1; d < 16; d <<= 1) {
    #pragma unroll
    for (int r = 0; r < 4; ++r) {
      float om1 = __shfl_xor(m1[r], d);
      float om2 = __shfl_xor(m2[r], d);
      int   oc1 = __shfl_xor(c1[r], d);
      float mx = fmaxf(m1[r], om1);
      m2[r] = fminf(fminf(m2[r], om2), mx);
      bool take = (om1 < m1[r]) || (om1 == m1[r] && oc1 < c1[r]);
      m1[r] = take ? om1 : m1[r];
      c1[r] = take ? oc1 : c1[r];
    }
  }
  if (l15 < 4) {
    const int r = l15;
    const int row = waverow + q * 4 + r;
    out_idx[row] = (unsigned)c1[r];
    if (m2[r] - m1[r] < MARGIN) {
      unsigned pos = atomicAdd(counter, 1u);
      list[pos] = (unsigned)row;
    }
  }
}

// ---------------- K3: fp64 true-argmin fallback (flagged rows only) ----------------
__global__ void k_fallback(const float* __restrict__ z, const float* __restrict__ cb,
                           const unsigned* __restrict__ list,
                           const unsigned* __restrict__ counter,
                           unsigned* __restrict__ out_idx) {
  const unsigned count = *counter;
  if (count == 0) return;
  const int t = threadIdx.x, lane = t & 63, w = t >> 6;
  const unsigned gw = blockIdx.x * 4 + w;              // 1024 waves
  for (unsigned g = gw; g < count; g += 1024) {
    const unsigned row = list[g];
    const float* zr = z + (size_t)row * DIMS;
    double best = 1e300; int bc = 0;
    for (int ci = 0; ci < 16; ++ci) {                  // in-lane cols ascending
      const int col = ci * 64 + lane;
      const float* cp = cb + (size_t)col * DIMS;
      double a0 = 0, a1 = 0, a2 = 0, a3 = 0, q0 = 0, q1 = 0;
      #pragma unroll 4
      for (int k = 0; k < DIMS; k += 4) {
        v4f zz = *(const v4f*)(zr + k);
        v4f cc = *(const v4f*)(cp + k);
        a0 = fma((double)zz[0], (double)cc[0], a0);
        a1 = fma((double)zz[1], (double)cc[1], a1);
        a2 = fma((double)zz[2], (double)cc[2], a2);
        a3 = fma((double)zz[3], (double)cc[3], a3);
        q0 = fma((double)cc[0], (double)cc[0], q0);
        q1 = fma((double)cc[1], (double)cc[1], q1);
        q0 = fma((double)cc[2], (double)cc[2], q0);
        q1 = fma((double)cc[3], (double)cc[3], q1);
      }
      double cost = (q0 + q1) - 2.0 * ((a0 + a1) + (a2 + a3));
      if (cost < best) { best = cost; bc = col; }      // strict <: lowest col
    }
    #pragma unroll
    for (int d = 1; d < 64; d <<= 1) {
      double ob = __shfl_xor(best, d);
      int    oc = __shfl_xor(bc, d);
      if (ob < best || (ob == best && oc < bc)) { best = ob; bc = oc; }
    }
    if (lane == 0) out_idx[row] = (unsigned)bc;
  }
}

// ---------------- K4: gather z_q + histogram ----------------
__global__ void k_gather(const float* __restrict__ cb, const unsigned* __restrict__ idx,
                         float* __restrict__ outz, unsigned* __restrict__ hist) {
  const int t = threadIdx.x, lane = t & 63, w = t >> 6;
  const int row = blockIdx.x * 4 + w;
  const unsigned id = idx[row];
  v4f v = *(const v4f*)(cb + (size_t)id * DIMS + lane * 4);
  *(v4f*)(outz + (size_t)row * DIMS + lane * 4) = v;
  if (lane == 0) atomicAdd(hist + id, 1u);
}

// ---------------- K5: loss + perplexity ----------------
__global__ void k_stats(const unsigned* __restrict__ hist, float* __restrict__ out) {
  const int t = threadIdx.x;
  float s = 0.f;
  for (int i = t; i < N_DICT; i += 256) {
    float p = (float)hist[i] * (1.0f / (float)N_ROWS);
    s += p * logf(p + 1e-10f);
  }
  #pragma unroll
  for (int d = 1; d < 64; d <<= 1) s += __shfl_xor(s, d);
  __shared__ float ls[4];
  if ((t & 63) == 0) ls[t >> 6] = s;
  __syncthreads();
  if (t == 0) {
    float tot = ls[0] + ls[1] + ls[2] + ls[3];
    out[16777216] = 0.0f;          // loss (eval)
    out[16777217] = expf(-tot);    // perplexity
  }
}

extern "C" void kernel_launch(void* const* d_in, const int* in_sizes, int n_in,
                              void* d_out, int out_size, void* d_ws, size_t ws_size,
                              hipStream_t stream) {
  const float* z  = (const float*)d_in[0];
  const float* cb = (const float*)d_in[1];
  float* out = (float*)d_out;
  char* ws = (char*)d_ws;
  _Float16* swz_h   = (_Float16*)ws;                   // 512 KB (fragment order)
  _Float16* swz_l   = (_Float16*)(ws + 524288);        // 512 KB
  float*    cnA     = (float*)(ws + 1048576);          // 4 KB
  unsigned* idx     = (unsigned*)(ws + 1052672);       // 256 KB
  unsigned* list    = (unsigned*)(ws + 1314816);       // 256 KB
  unsigned* hist    = (unsigned*)(ws + 1576960);       // 4 KB
  unsigned* counter = (unsigned*)(ws + 1581056);

  k_prep    <<<256,   256, 0, stream>>>(cb, swz_h, swz_l, cnA, hist, counter);
  k_main    <<<1024,  256, 0, stream>>>(z, swz_h, swz_l, cnA, idx, list, counter);
  k_fallback<<<256,   256, 0, stream>>>(z, cb, list, counter, idx);
  k_gather  <<<16384, 256, 0, stream>>>(cb, idx, out, hist);
  k_stats   <<<1,     256, 0, stream>>>(hist, out);
}

// Round 6
// 417.674 us; speedup vs baseline: 3.3734x; 1.1799x over previous
//
#include <hip/hip_runtime.h>
#include <hip/hip_bf16.h>
#include <stdint.h>

// WSVectorQuantizer: N=65536 rows (D=256) vs K=1024 codewords.
// v6: split-fp16 MFMA, swizzled B (coalesced), m=2 (32 rows/wave) to double
// arithmetic intensity per B-byte: per kk 8 B-loads -> 24 MFMAs.

typedef float  v4f __attribute__((ext_vector_type(4)));
typedef _Float16 v8h __attribute__((ext_vector_type(8)));
typedef _Float16 v4h __attribute__((ext_vector_type(4)));

#define N_ROWS 65536
#define N_DICT 1024
#define DIMS   256
#define MARGIN 4e-3f   // ~10x worst-tail of split-fp16 error (~4e-4)

// ---------------- K1: prep ----------------
// codebook -> (h,l) split-fp16 stored in MFMA B-fragment order:
// off = ((c*8+kk)*4+t4)*512 + lane*8 + j, lane=q*16+l15 -> col=c*64+t4*16+l15,
// k = kk*32+q*8+j.
__global__ void k_prep(const float* __restrict__ cb, _Float16* __restrict__ swz_h,
                       _Float16* __restrict__ swz_l, float* __restrict__ cnA,
                       unsigned* __restrict__ hist, unsigned* __restrict__ counter) {
  const int b = blockIdx.x, t = threadIdx.x;
  if (b == 0) {
    for (int i = t; i < N_DICT; i += 256) hist[i] = 0u;
    if (t == 0) *counter = 0u;
  }
  const int gid = b * 256 + t;                 // 65536 threads x 4 elems
  const int col = gid >> 6;
  const int k0  = (gid & 63) * 4;
  v4f v = ((const v4f*)cb)[gid];
  v4h h, l;
  #pragma unroll
  for (int j = 0; j < 4; ++j) {
    h[j] = (_Float16)v[j];
    float r = v[j] - (float)h[j];              // exact residual
    l[j] = (_Float16)r;                        // |err| <= 2^-22 |v|
  }
  const int c = col >> 6, t4 = (col >> 4) & 3, l15 = col & 15;
  const int kk = k0 >> 5, q = (k0 >> 3) & 3, j0 = k0 & 7;
  const size_t off = (size_t)(((c * 8 + kk) * 4 + t4) * 512 + (q * 16 + l15) * 8 + j0);
  *(v4h*)(swz_h + off) = h;
  *(v4h*)(swz_l + off) = l;
  // exact ||c||^2 (fp64 acc): one wave per codeword
  const int lane = t & 63, w = t >> 6;
  const int row = b * 4 + w;
  v4f u = ((const v4f*)cb)[row * 64 + lane];
  double s = (double)u[0]*u[0] + (double)u[1]*u[1]
           + (double)u[2]*u[2] + (double)u[3]*u[3];
  #pragma unroll
  for (int d = 1; d < 64; d <<= 1) s += __shfl_xor(s, d);
  if (lane == 0) cnA[row] = (float)s;
}

// ---------------- K2: main split-fp16 MFMA argmin, m=2 ----------------
// 512 blocks x 256 thr (4 waves). Wave owns 32 rows (2 m-tiles); A h/l frags
// persistent (~128 regs). 16 chunks of 64 cols; per kk: 8 coalesced 1KiB
// B-loads, 24 MFMAs. Track (min1,col1,min2) per 8 states; in-lane cols
// ascending -> strict < keeps lowest col (np tie rule).
__launch_bounds__(256, 2)
__global__ void k_main(const float* __restrict__ z, const _Float16* __restrict__ swz_h,
                       const _Float16* __restrict__ swz_l, const float* __restrict__ cnA,
                       unsigned* __restrict__ out_idx,
                       unsigned* __restrict__ list, unsigned* __restrict__ counter) {
  const int t = threadIdx.x, lane = t & 63, w = t >> 6;
  const int l15 = lane & 15, q = lane >> 4;
  const int waverow = (blockIdx.x * 4 + w) * 32;

  // A fragments: lane holds z[waverow+m*16+l15][kk*32 + q*8 .. +8], split h/l
  v8h ah[2][8], al[2][8];
  #pragma unroll
  for (int m = 0; m < 2; ++m) {
    const float* zp = z + (size_t)(waverow + m * 16 + l15) * DIMS + q * 8;
    #pragma unroll
    for (int kk = 0; kk < 8; ++kk) {
      v4f f0 = *(const v4f*)(zp + kk * 32);
      v4f f1 = *(const v4f*)(zp + kk * 32 + 4);
      v8h hh, ll;
      #pragma unroll
      for (int j = 0; j < 4; ++j) {
        hh[j] = (_Float16)f0[j];
        float r = f0[j] - (float)hh[j];
        ll[j] = (_Float16)r;
        hh[4 + j] = (_Float16)f1[j];
        r = f1[j] - (float)hh[4 + j];
        ll[4 + j] = (_Float16)r;
      }
      ah[m][kk] = hh; al[m][kk] = ll;
    }
  }

  // state s = m*4+r covers row = waverow + m*16 + q*4 + r
  float m1[8], m2[8]; int c1[8];
  #pragma unroll
  for (int s = 0; s < 8; ++s) { m1[s] = 1e30f; m2[s] = 1e30f; c1[s] = 0; }

  for (int c = 0; c < 16; ++c) {
    const int n0 = c * 64;
    float cn[4]; int colv[4];
    #pragma unroll
    for (int t4 = 0; t4 < 4; ++t4) {
      colv[t4] = n0 + t4 * 16 + l15;
      cn[t4] = cnA[colv[t4]];
    }
    v4f acc[2][4];
    #pragma unroll
    for (int m = 0; m < 2; ++m)
      #pragma unroll
      for (int t4 = 0; t4 < 4; ++t4) acc[m][t4] = (v4f){0.f, 0.f, 0.f, 0.f};

    // coalesced fragment streams: 32 x 1KiB per chunk, h and l
    const _Float16* bh = swz_h + (size_t)(c * 32) * 512 + lane * 8;
    const _Float16* bl = swz_l + (size_t)(c * 32) * 512 + lane * 8;
    #pragma unroll
    for (int kk = 0; kk < 8; ++kk) {
      v8h b_h[4], b_l[4];
      #pragma unroll
      for (int t4 = 0; t4 < 4; ++t4)
        b_h[t4] = *(const v8h*)(bh + (size_t)(kk * 4 + t4) * 512);
      #pragma unroll
      for (int t4 = 0; t4 < 4; ++t4)
        b_l[t4] = *(const v8h*)(bl + (size_t)(kk * 4 + t4) * 512);
      #pragma unroll
      for (int m = 0; m < 2; ++m) {
        #pragma unroll
        for (int t4 = 0; t4 < 4; ++t4)
          acc[m][t4] = __builtin_amdgcn_mfma_f32_16x16x32_f16(ah[m][kk], b_h[t4], acc[m][t4], 0, 0, 0);
        #pragma unroll
        for (int t4 = 0; t4 < 4; ++t4)
          acc[m][t4] = __builtin_amdgcn_mfma_f32_16x16x32_f16(al[m][kk], b_h[t4], acc[m][t4], 0, 0, 0);
        #pragma unroll
        for (int t4 = 0; t4 < 4; ++t4)
          acc[m][t4] = __builtin_amdgcn_mfma_f32_16x16x32_f16(ah[m][kk], b_l[t4], acc[m][t4], 0, 0, 0);
      }
    }
    #pragma unroll
    for (int m = 0; m < 2; ++m)
      #pragma unroll
      for (int t4 = 0; t4 < 4; ++t4)
        #pragma unroll
        for (int r = 0; r < 4; ++r) {
          float cost = fmaf(acc[m][t4][r], -2.0f, cn[t4]);
          const int s = m * 4 + r;
          bool lt = cost < m1[s];
          m2[s] = fminf(m2[s], fmaxf(m1[s], cost));
          m1[s] = fminf(m1[s], cost);
          c1[s] = lt ? colv[t4] : c1[s];
        }
  }

  // butterfly merge over the 16 lanes sharing q (lexicographic on (m1, col))
  #pragma unroll
  for (int d = 1; d < 16; d <<= 1) {
    #pragma unroll
    for (int s = 0; s < 8; ++s) {
      float om1 = __shfl_xor(m1[s], d);
      float om2 = __shfl_xor(m2[s], d);
      int   oc1 = __shfl_xor(c1[s], d);
      float mx = fmaxf(m1[s], om1);
      m2[s] = fminf(fminf(m2[s], om2), mx);
      bool take = (om1 < m1[s]) || (om1 == m1[s] && oc1 < c1[s]);
      m1[s] = take ? om1 : m1[s];
      c1[s] = take ? oc1 : c1[s];
    }
  }
  if (l15 < 8) {
    const int s = l15, m = s >> 2, r = s & 3;
    const int row = waverow + m * 16 + q * 4 + r;
    out_idx[row] = (unsigned)c1[s];
    if (m2[s] - m1[s] < MARGIN) {
      unsigned pos = atomicAdd(counter, 1u);
      list[pos] = (unsigned)row;
    }
  }
}

// ---------------- K3: fp64 true-argmin fallback (flagged rows only) ----------------
__global__ void k_fallback(const float* __restrict__ z, const float* __restrict__ cb,
                           const unsigned* __restrict__ list,
                           const unsigned* __restrict__ counter,
                           unsigned* __restrict__ out_idx) {
  const unsigned count = *counter;
  if (count == 0) return;
  const int t = threadIdx.x, lane = t & 63, w = t >> 6;
  const unsigned gw = blockIdx.x * 4 + w;              // 1024 waves
  for (unsigned g = gw; g < count; g += 1024) {
    const unsigned row = list[g];
    const float* zr = z + (size_t)row * DIMS;
    double best = 1e300; int bc = 0;
    for (int ci = 0; ci < 16; ++ci) {                  // in-lane cols ascending
      const int col = ci * 64 + lane;
      const float* cp = cb + (size_t)col * DIMS;
      double a0 = 0, a1 = 0, a2 = 0, a3 = 0, q0 = 0, q1 = 0;
      #pragma unroll 4
      for (int k = 0; k < DIMS; k += 4) {
        v4f zz = *(const v4f*)(zr + k);
        v4f cc = *(const v4f*)(cp + k);
        a0 = fma((double)zz[0], (double)cc[0], a0);
        a1 = fma((double)zz[1], (double)cc[1], a1);
        a2 = fma((double)zz[2], (double)cc[2], a2);
        a3 = fma((double)zz[3], (double)cc[3], a3);
        q0 = fma((double)cc[0], (double)cc[0], q0);
        q1 = fma((double)cc[1], (double)cc[1], q1);
        q0 = fma((double)cc[2], (double)cc[2], q0);
        q1 = fma((double)cc[3], (double)cc[3], q1);
      }
      double cost = (q0 + q1) - 2.0 * ((a0 + a1) + (a2 + a3));
      if (cost < best) { best = cost; bc = col; }      // strict <: lowest col
    }
    #pragma unroll
    for (int d = 1; d < 64; d <<= 1) {
      double ob = __shfl_xor(best, d);
      int    oc = __shfl_xor(bc, d);
      if (ob < best || (ob == best && oc < bc)) { best = ob; bc = oc; }
    }
    if (lane == 0) out_idx[row] = (unsigned)bc;
  }
}

// ---------------- K4: gather z_q + histogram ----------------
// 1024 blocks x 256 thr; wave w handles 16 consecutive rows (16 KiB write).
__global__ void k_gather(const float* __restrict__ cb, const unsigned* __restrict__ idx,
                         float* __restrict__ outz, unsigned* __restrict__ hist) {
  const int t = threadIdx.x, lane = t & 63, w = t >> 6;
  const int base = (blockIdx.x * 4 + w) * 16;
  #pragma unroll 4
  for (int r = 0; r < 16; ++r) {
    const int row = base + r;
    const unsigned id = idx[row];
    v4f v = *(const v4f*)(cb + (size_t)id * DIMS + lane * 4);
    *(v4f*)(outz + (size_t)row * DIMS + lane * 4) = v;
    if (lane == (r & 63)) atomicAdd(hist + id, 1u);
  }
}

// ---------------- K5: loss + perplexity ----------------
__global__ void k_stats(const unsigned* __restrict__ hist, float* __restrict__ out) {
  const int t = threadIdx.x;
  float s = 0.f;
  for (int i = t; i < N_DICT; i += 256) {
    float p = (float)hist[i] * (1.0f / (float)N_ROWS);
    s += p * logf(p + 1e-10f);
  }
  #pragma unroll
  for (int d = 1; d < 64; d <<= 1) s += __shfl_xor(s, d);
  __shared__ float ls[4];
  if ((t & 63) == 0) ls[t >> 6] = s;
  __syncthreads();
  if (t == 0) {
    float tot = ls[0] + ls[1] + ls[2] + ls[3];
    out[16777216] = 0.0f;          // loss (eval)
    out[16777217] = expf(-tot);    // perplexity
  }
}

extern "C" void kernel_launch(void* const* d_in, const int* in_sizes, int n_in,
                              void* d_out, int out_size, void* d_ws, size_t ws_size,
                              hipStream_t stream) {
  const float* z  = (const float*)d_in[0];
  const float* cb = (const float*)d_in[1];
  float* out = (float*)d_out;
  char* ws = (char*)d_ws;
  _Float16* swz_h   = (_Float16*)ws;                   // 512 KB (fragment order)
  _Float16* swz_l   = (_Float16*)(ws + 524288);        // 512 KB
  float*    cnA     = (float*)(ws + 1048576);          // 4 KB
  unsigned* idx     = (unsigned*)(ws + 1052672);       // 256 KB
  unsigned* list    = (unsigned*)(ws + 1314816);       // 256 KB
  unsigned* hist    = (unsigned*)(ws + 1576960);       // 4 KB
  unsigned* counter = (unsigned*)(ws + 1581056);

  k_prep    <<<256,   256, 0, stream>>>(cb, swz_h, swz_l, cnA, hist, counter);
  k_main    <<<512,   256, 0, stream>>>(z, swz_h, swz_l, cnA, idx, list, counter);
  k_fallback<<<256,   256, 0, stream>>>(z, cb, list, counter, idx);
  k_gather  <<<1024,  256, 0, stream>>>(cb, idx, out, hist);
  k_stats   <<<1,     256, 0, stream>>>(hist, out);
}